// Round 6
// baseline (1112.957 us; speedup 1.0000x reference)
//
#include <hip/hip_runtime.h>

#define B_   128
#define T_   40
#define E_   512
#define H_   1024
#define V_   10000
#define IN_  2048
#define G4_  4096
#define NPAD 10112   // 79 * 128
#define NBLK 64      // persistent recurrence grid (<= 256 CUs, 1 block/CU by LDS)

typedef __attribute__((ext_vector_type(8))) short bf16x8;
typedef __attribute__((ext_vector_type(4))) float f32x4;

__device__ inline unsigned short f2bf(float x) {
    unsigned u = __float_as_uint(x);
    u += 0x7fff + ((u >> 16) & 1);          // RNE
    return (unsigned short)(u >> 16);
}
__device__ inline float bf2f(unsigned short u) {
    return __uint_as_float(((unsigned)u) << 16);
}
__device__ inline float sigf(float x) { return 1.f / (1.f + __expf(-x)); }
__device__ inline float tanhfast(float x) {
    x = fminf(fmaxf(x, -15.f), 15.f);
    float e = __expf(2.f * x);
    return (e - 1.f) / (e + 1.f);
}

// ---------------------------------------------------------------------------
// Stage ROWSx64 bf16 tile global -> LDS via global_load_lds(16B), 4-wave form.
// LDS dest linear chunk c = row*8 + kc; global source chunk pre-swizzled
// (kc ^= row&7) so the swizzled frag() ds_read_b128 is bank-conflict-free.
// ---------------------------------------------------------------------------
template <int NINST>   // NINST = rows/64: 2 -> 128 rows, 1 -> 64 rows
__device__ inline void stageT(const unsigned short* __restrict__ src, int ld,
                              char* lbuf, int wave, int lane) {
#pragma unroll
    for (int i = 0; i < NINST * 2; ++i) {
        int c = i * 256 + wave * 64 + lane;
        int row = c >> 3, kc = c & 7;
        const unsigned short* g = src + (size_t)row * ld + ((kc ^ (row & 7)) << 3);
        __builtin_amdgcn_global_load_lds(
            (const __attribute__((address_space(1))) void*)g,
            (__attribute__((address_space(3))) void*)(lbuf + ((i * 256 + wave * 64) << 4)),
            16, 0, 0);
    }
}
// swizzled frag read: row-major [R][64] bf16 tile, 8 bf16 at (row, kc*8)
__device__ inline bf16x8 frag(const char* base, int row, int kc) {
    return *(const bf16x8*)(base + (((row << 3) + (kc ^ (row & 7))) << 4));
}

// ---------------------------------------------------------------------------
// bf16 MFMA GEMM: C = A[M][K] * B[N][K]^T (+bias), 128x128 tile, BK=64,
// 4 waves (2x2, 64x64 each), double-buffered global_load_lds (1 barrier/K-step).
// EPI 0 (gx):     gx_bf[m][n] = bf16(acc + gfeatB[m&127][n])   (bf16 out)
// EPI 1 (logits): out[b][t][n] = acc + lin_b[n], m = t*128+b, guard n < V_
// ---------------------------------------------------------------------------
template <int EPI>
__global__ __launch_bounds__(256) void gemm_bf16(const unsigned short* __restrict__ A, int lda,
                                                 const unsigned short* __restrict__ Bm, int ldb,
                                                 const float* __restrict__ bias,
                                                 void* __restrict__ Cout, int K) {
    __shared__ char lds[67584];   // union: 2x(16K A + 16K B) staging | 128x132 f32 exchange
    int m0 = blockIdx.x * 128, n0 = blockIdx.y * 128;
    int tid = threadIdx.x, lane = tid & 63, wave = tid >> 6;
    int wm = (wave >> 1) * 64, wn = (wave & 1) * 64;
    const unsigned short* Ab = A + (size_t)m0 * lda;
    const unsigned short* Bb = Bm + (size_t)n0 * ldb;

    f32x4 acc[4][4];
#pragma unroll
    for (int i = 0; i < 4; ++i)
#pragma unroll
        for (int j = 0; j < 4; ++j) acc[i][j] = (f32x4){0.f, 0.f, 0.f, 0.f};

    stageT<2>(Ab, lda, lds, wave, lane);
    stageT<2>(Bb, ldb, lds + 16384, wave, lane);
    __syncthreads();

    int nk = K >> 6;
    for (int kt = 0; kt < nk; ++kt) {
        int cur = kt & 1;
        if (kt + 1 < nk) {
            stageT<2>(Ab + ((kt + 1) << 6), lda, lds + (cur ^ 1) * 32768, wave, lane);
            stageT<2>(Bb + ((kt + 1) << 6), ldb, lds + (cur ^ 1) * 32768 + 16384, wave, lane);
        }
        const char* Ac = lds + cur * 32768;
        const char* Bc = Ac + 16384;
#pragma unroll
        for (int kk = 0; kk < 2; ++kk) {
            int kc = (kk << 2) + (lane >> 4);
            bf16x8 af[4], bfr[4];
#pragma unroll
            for (int i = 0; i < 4; ++i) af[i] = frag(Ac, wm + i * 16 + (lane & 15), kc);
#pragma unroll
            for (int j = 0; j < 4; ++j) bfr[j] = frag(Bc, wn + j * 16 + (lane & 15), kc);
#pragma unroll
            for (int i = 0; i < 4; ++i)
#pragma unroll
                for (int j = 0; j < 4; ++j)
                    acc[i][j] = __builtin_amdgcn_mfma_f32_16x16x32_bf16(af[i], bfr[j], acc[i][j], 0, 0, 0);
        }
        __syncthreads();
    }

    // ---- epilogue: D-frags -> LDS exchange -> coalesced stores ----
    float(*ex)[132] = (float(*)[132])lds;
#pragma unroll
    for (int i = 0; i < 4; ++i) {
        int r = wm + i * 16 + (lane >> 4) * 4;     // D: row = (l>>4)*4 + reg
#pragma unroll
        for (int j = 0; j < 4; ++j) {
            int c = wn + j * 16 + (lane & 15);     // D: col = l&15
#pragma unroll
            for (int q = 0; q < 4; ++q) ex[r + q][c] = acc[i][j][q];
        }
    }
    __syncthreads();
#pragma unroll
    for (int it = 0; it < 16; ++it) {
        int chunk = it * 256 + tid;
        int r = chunk >> 5, c4 = (chunk & 31) << 2;
        float4 v = *(const float4*)&ex[r][c4];
        if (EPI == 0) {
            const float* gb = bias + (((size_t)((m0 + r) & 127)) << 12) + (n0 + c4);
            float4 b4 = *(const float4*)gb;
            ushort4 u = {f2bf(v.x + b4.x), f2bf(v.y + b4.y),
                         f2bf(v.z + b4.z), f2bf(v.w + b4.w)};
            *(ushort4*)((unsigned short*)Cout + (((size_t)(m0 + r)) << 12) + n0 + c4) = u;
        } else {
            int n = n0 + c4;
            if (n < V_) {
                float4 b4 = *(const float4*)(bias + n);
                v.x += b4.x; v.y += b4.y; v.z += b4.z; v.w += b4.w;
                int m = m0 + r, tt = m >> 7, b = m & 127;
                *(float4*)((float*)Cout + ((size_t)b * T_ + tt) * V_ + n) = v;
            }
        }
    }
}

// ---------------------------------------------------------------------------
// Persistent LSTM recurrence: ONE kernel for all 40 steps.
// 64 blocks x 512 threads (8 waves). Block blk owns hcols [blk*16,blk*16+16)
// x 4 gates = 64 gate-cols; its w_hh slice (64x1024 bf16 = 128 KB) is pinned
// in LDS for all steps. h (A operand) double-buffered per 128x64 K-tile.
// c lives in registers (4 f32/thread). Per step: MFMA -> gates -> h[s+1]
// written to a FRESH global slot -> device-scope grid barrier.
// Wave w computes batch rows [w*16, w*16+16); acc[j] IS gate j.
// ---------------------------------------------------------------------------
__global__ __launch_bounds__(512, 1) void lstm_persist(
        unsigned short* __restrict__ hs,          // [41][128][1024] bf16, hs[0]=0
        const unsigned short* __restrict__ gx,    // [40][128][4096] bf16
        const unsigned short* __restrict__ wperm, // [4096][1024] bf16 block-sliced
        unsigned* __restrict__ bar) {             // zeroed before launch
    __shared__ char wlds[131072];   // 16 K-tiles of [64][64] bf16, swizzled
    __shared__ char hlds[32768];    // 2 x [128][64] bf16, swizzled
    int tid = threadIdx.x, lane = tid & 63, wave = tid >> 6;
    int blk = blockIdx.x;
    int hc0 = blk << 4;
    const unsigned short* wsrc = wperm + ((size_t)blk << 16);   // 64 rows x 1024

    // ---- pin w slice in LDS (once): 16 tiles, 512 chunks each -> 1/thread ----
#pragma unroll
    for (int kt = 0; kt < 16; ++kt) {
        int c = wave * 64 + lane;
        int row = c >> 3, kc = c & 7;
        const unsigned short* g = wsrc + (size_t)row * H_ + (kt << 6) + ((kc ^ (row & 7)) << 3);
        __builtin_amdgcn_global_load_lds(
            (const __attribute__((address_space(1))) void*)g,
            (__attribute__((address_space(3))) void*)(wlds + (kt << 13) + ((wave * 64) << 4)),
            16, 0, 0);
    }

    int hcol = hc0 + (lane & 15);
    int rbase = (wave << 4) + ((lane >> 4) << 2);   // batch row base for this thread
    float creg[4] = {0.f, 0.f, 0.f, 0.f};

    for (int s = 0; s < T_; ++s) {
        const unsigned short* hstep = hs + ((size_t)s << 17);
        // stage h K-tile 0 (128x64): 1024 chunks, 2/thread
#pragma unroll
        for (int i = 0; i < 2; ++i) {
            int c = i * 512 + wave * 64 + lane;
            int row = c >> 3, kc = c & 7;
            const unsigned short* g = hstep + (size_t)row * H_ + ((kc ^ (row & 7)) << 3);
            __builtin_amdgcn_global_load_lds(
                (const __attribute__((address_space(1))) void*)g,
                (__attribute__((address_space(3))) void*)(hlds + ((i * 512 + wave * 64) << 4)),
                16, 0, 0);
        }
        // acc init from gx (overlaps with staging)
        f32x4 acc[4];
#pragma unroll
        for (int j = 0; j < 4; ++j) {
            int g = (j << 10) + hcol;
#pragma unroll
            for (int q = 0; q < 4; ++q)
                acc[j][q] = bf2f(gx[(((size_t)(s * B_ + rbase + q)) << 12) + g]);
        }
        __syncthreads();

        for (int kt = 0; kt < 16; ++kt) {
            if (kt < 15) {
                const unsigned short* hn = hstep + ((kt + 1) << 6);
                char* dst = hlds + (((kt + 1) & 1) << 14);
#pragma unroll
                for (int i = 0; i < 2; ++i) {
                    int c = i * 512 + wave * 64 + lane;
                    int row = c >> 3, kc = c & 7;
                    const unsigned short* g = hn + (size_t)row * H_ + ((kc ^ (row & 7)) << 3);
                    __builtin_amdgcn_global_load_lds(
                        (const __attribute__((address_space(1))) void*)g,
                        (__attribute__((address_space(3))) void*)(dst + ((i * 512 + wave * 64) << 4)),
                        16, 0, 0);
                }
            }
            const char* cb = hlds + ((kt & 1) << 14);
            const char* wt = wlds + (kt << 13);
#pragma unroll
            for (int kk = 0; kk < 2; ++kk) {
                int kc = (kk << 2) + (lane >> 4);
                bf16x8 af = frag(cb, (wave << 4) + (lane & 15), kc);
#pragma unroll
                for (int j = 0; j < 4; ++j) {
                    bf16x8 bf = frag(wt, (j << 4) + (lane & 15), kc);
                    acc[j] = __builtin_amdgcn_mfma_f32_16x16x32_bf16(af, bf, acc[j], 0, 0, 0);
                }
            }
            __syncthreads();
        }

        // gates -> c,h update; write h[s+1] to a fresh slot
        unsigned short* hnext = hs + ((size_t)(s + 1) << 17);
#pragma unroll
        for (int q = 0; q < 4; ++q) {
            float iv = sigf(acc[0][q]);
            float fv = sigf(acc[1][q]);
            float gv = tanhfast(acc[2][q]);
            float ov = sigf(acc[3][q]);
            float c = fv * creg[q] + iv * gv;
            creg[q] = c;
            hnext[(((size_t)(rbase + q)) << 10) + hcol] = f2bf(ov * tanhfast(c));
        }

        // device-scope grid barrier (release h stores, acquire for next step)
        __syncthreads();                       // all block h-stores issued & drained
        if (tid == 0) {
            __threadfence();                   // flush to device-coherent point
            atomicAdd(bar, 1u);
            unsigned target = (unsigned)NBLK * (unsigned)(s + 1);
            while (__hip_atomic_load(bar, __ATOMIC_RELAXED, __HIP_MEMORY_SCOPE_AGENT) < target)
                __builtin_amdgcn_s_sleep(2);
            __threadfence();                   // acquire: invalidate stale caches
        }
        __syncthreads();
    }
}

// ---------------------------------------------------------------------------
// prep kernels
// ---------------------------------------------------------------------------
__global__ __launch_bounds__(256) void zero_init(unsigned short* h0, unsigned* bar) {
    int i = blockIdx.x * 256 + threadIdx.x;       // 512 blocks -> 131072
    h0[i] = 0;
    if (i == 0) *bar = 0;
}

__global__ __launch_bounds__(256) void feats_kernel(const float* __restrict__ X,
                                                    const float* __restrict__ W,
                                                    const float* __restrict__ bias,
                                                    float* __restrict__ out) {
    __shared__ float xs[IN_];
    int b = blockIdx.x, eg = blockIdx.y;
    const float4* xr = (const float4*)(X + (size_t)b * IN_);
    for (int i = threadIdx.x; i < IN_ / 4; i += 256) ((float4*)xs)[i] = xr[i];
    __syncthreads();
    int e = eg * 256 + threadIdx.x;
    const float* wr = W + (size_t)e * IN_;
    float acc = 0.f;
#pragma unroll 4
    for (int k = 0; k < IN_; k += 4) {
        float4 w = *(const float4*)(wr + k);
        acc += w.x * xs[k] + w.y * xs[k + 1] + w.z * xs[k + 2] + w.w * xs[k + 3];
    }
    out[(size_t)b * E_ + e] = acc + bias[e];
}

// gfeatB[b][g] = feats[b] . w_ih[g][0:512] + b_ih[g] + b_hh[g]
__global__ __launch_bounds__(256) void gfeatB_kernel(const float* __restrict__ feats,
                                                     const float* __restrict__ w_ih,
                                                     const float* __restrict__ b_ih,
                                                     const float* __restrict__ b_hh,
                                                     float* __restrict__ gfeatB) {
    __shared__ float fs[8][E_];
    int bg = blockIdx.x * 8, gg = blockIdx.y * 256;
    for (int i = threadIdx.x; i < 8 * E_ / 4; i += 256) {
        int b = i / (E_ / 4), k4 = i % (E_ / 4);
        ((float4*)fs[b])[k4] = ((const float4*)(feats + (size_t)(bg + b) * E_))[k4];
    }
    __syncthreads();
    int g = gg + threadIdx.x;
    const float* wr = w_ih + (size_t)g * (2 * E_);
    float acc[8] = {};
    for (int k = 0; k < E_; k += 4) {
        float4 w = *(const float4*)(wr + k);
#pragma unroll
        for (int b = 0; b < 8; ++b) {
            float4 f = *(const float4*)&fs[b][k];
            acc[b] += w.x * f.x + w.y * f.y + w.z * f.z + w.w * f.w;
        }
    }
    float bb = b_ih[g] + b_hh[g];
#pragma unroll
    for (int b = 0; b < 8; ++b)
        gfeatB[(size_t)(bg + b) * G4_ + g] = acc[b] + bb;
}

// emb_bf[m][0:512] = bf16(lembed[labels[b][t]]), m = t*128+b
__global__ __launch_bounds__(128) void gather_bf(const int* __restrict__ labels,
                                                 const float* __restrict__ lembed,
                                                 unsigned short* __restrict__ emb) {
    int m = blockIdx.x, t = m >> 7, b = m & 127;
    int lab = labels[b * T_ + t];
    int c = threadIdx.x * 4;
    float4 v = *(const float4*)(lembed + (size_t)lab * E_ + c);
    ushort4 u = {f2bf(v.x), f2bf(v.y), f2bf(v.z), f2bf(v.w)};
    *(ushort4*)(emb + (size_t)m * E_ + c) = u;
}

// lin_w [10000][1024] f32 -> [10112][1024] bf16, zero-padded rows
__global__ __launch_bounds__(256) void conv_pad_lin(const float* __restrict__ w,
                                                    unsigned short* __restrict__ o) {
    int r = blockIdx.x, c = threadIdx.x * 4;
    float4 v = make_float4(0.f, 0.f, 0.f, 0.f);
    if (r < V_) v = *(const float4*)(w + (size_t)r * H_ + c);
    ushort4 u = {f2bf(v.x), f2bf(v.y), f2bf(v.z), f2bf(v.w)};
    *(ushort4*)(o + (size_t)r * H_ + c) = u;
}

// w_hh [4096][1024] -> wperm bf16: dst row d = blk*64 + r holds
// w_hh row (r>>4)*1024 + blk*16 + (r&15)
__global__ __launch_bounds__(256) void conv_whh(const float* __restrict__ w,
                                                unsigned short* __restrict__ o) {
    int d = blockIdx.x, blk = d >> 6, r = d & 63;
    int s = ((r >> 4) << 10) + (blk << 4) + (r & 15);
    int c = threadIdx.x * 4;
    float4 v = *(const float4*)(w + (size_t)s * H_ + c);
    ushort4 u = {f2bf(v.x), f2bf(v.y), f2bf(v.z), f2bf(v.w)};
    *(ushort4*)(o + (size_t)d * H_ + c) = u;
}

// w_ih cols 512..1023 -> w_ihe bf16 [4096][512]
__global__ __launch_bounds__(128) void conv_wih(const float* __restrict__ w,
                                                unsigned short* __restrict__ o) {
    int g = blockIdx.x, c = threadIdx.x * 4;
    float4 v = *(const float4*)(w + (size_t)g * (2 * E_) + E_ + c);
    ushort4 u = {f2bf(v.x), f2bf(v.y), f2bf(v.z), f2bf(v.w)};
    *(ushort4*)(o + (size_t)g * E_ + c) = u;
}

// ---------------------------------------------------------------------------
extern "C" void kernel_launch(void* const* d_in, const int* in_sizes, int n_in,
                              void* d_out, int out_size, void* d_ws, size_t ws_size,
                              hipStream_t stream) {
    const float* X        = (const float*)d_in[0];
    const int*   labels   = (const int*)d_in[1];
    const float* fembed_w = (const float*)d_in[2];
    const float* fembed_b = (const float*)d_in[3];
    const float* lembed   = (const float*)d_in[4];
    const float* w_ih     = (const float*)d_in[5];
    const float* b_ih     = (const float*)d_in[6];
    const float* w_hh     = (const float*)d_in[7];
    const float* b_hh     = (const float*)d_in[8];
    const float* lin_w    = (const float*)d_in[9];
    const float* lin_b    = (const float*)d_in[10];
    float* out = (float*)d_out;

    // workspace layout (~94 MiB; round-1 proved >= ~119 MiB exists)
    char* ws = (char*)d_ws;
    unsigned short* hs_bf  = (unsigned short*)ws; ws += (size_t)(T_ + 1) * B_ * H_ * 2;
    float*          feats  = (float*)ws;          ws += (size_t)B_ * E_ * 4;
    float*          gfeatB = (float*)ws;          ws += (size_t)B_ * G4_ * 4;
    unsigned short* emb_bf = (unsigned short*)ws; ws += (size_t)T_ * B_ * E_ * 2;
    unsigned short* w_ihe  = (unsigned short*)ws; ws += (size_t)G4_ * E_ * 2;
    unsigned short* wperm  = (unsigned short*)ws; ws += (size_t)G4_ * H_ * 2;
    unsigned short* lin_wp = (unsigned short*)ws; ws += (size_t)NPAD * H_ * 2;
    unsigned short* gx     = (unsigned short*)ws; ws += (size_t)T_ * B_ * G4_ * 2;
    unsigned*       bar    = (unsigned*)ws;       ws += 64;

    // prep (independent)
    zero_init<<<512, 256, 0, stream>>>(hs_bf, bar);
    conv_whh<<<G4_, 256, 0, stream>>>(w_hh, wperm);
    conv_wih<<<G4_, 128, 0, stream>>>(w_ih, w_ihe);
    conv_pad_lin<<<NPAD, 256, 0, stream>>>(lin_w, lin_wp);
    gather_bf<<<T_ * B_, 128, 0, stream>>>(labels, lembed, emb_bf);
    feats_kernel<<<dim3(B_, 2), 256, 0, stream>>>(X, fembed_w, fembed_b, feats);
    gfeatB_kernel<<<dim3(16, 16), 256, 0, stream>>>(feats, w_ih, b_ih, b_hh, gfeatB);

    // gx[m][g] = bf16(emb_bf[m] . w_ihe[g] + gfeatB[m&127][g])  (M=5120,N=4096,K=512)
    gemm_bf16<0><<<dim3(40, 32), 256, 0, stream>>>(emb_bf, E_, w_ihe, E_, gfeatB, gx, E_);

    // whole recurrence: one persistent kernel, grid-synced per step
    lstm_persist<<<NBLK, 512, 0, stream>>>(hs_bf, gx, wperm, bar);

    // logits: out[b][t][v] = hs_bf[t+1][b] . lin_wp[v] + lin_b[v]
    gemm_bf16<1><<<dim3(40, 79), 256, 0, stream>>>(hs_bf + (size_t)B_ * H_, H_,
                                                   lin_wp, H_, lin_b, out, H_);
}